// Round 18
// baseline (204.244 us; speedup 1.0000x reference)
//
#include <hip/hip_runtime.h>
#include <hip/hip_bf16.h>

constexpr int NROW = 8192;
constexpr int INF  = 256;
constexpr int OUTF = 128;
constexpr int KSPLIT = 8;
constexpr int KCHUNK = NROW / KSPLIT; // 1024
constexpr int NIT    = KCHUNK / 64;   // 16 k-iterations per block
#define LOG2E 1.4426950408889634f

typedef __bf16 bf16x8 __attribute__((ext_vector_type(8)));
typedef float  f32x4  __attribute__((ext_vector_type(4)));
typedef int    i32x4  __attribute__((ext_vector_type(4)));
typedef unsigned long long u64;

// ---------------------------------------------------------------------------
// k1: h = x@W (f32 accum); f1 = (h@a1)*log2e, f2 = (h@a2)*log2e; ht = h^T bf16
// grid: NROW/32 blocks, 256 threads
// ---------------------------------------------------------------------------
__global__ __launch_bounds__(256) void k1(const float* __restrict__ x,
                                          const float* __restrict__ W,
                                          const float* __restrict__ a,
                                          __bf16* __restrict__ ht,
                                          float* __restrict__ f1,
                                          float* __restrict__ f2) {
  __shared__ float xs[32][INF];   // 32 KB
  __shared__ float hs[32][OUTF];  // 16 KB
  const int t  = threadIdx.x;
  const int i0 = blockIdx.x * 32;

  const f32x4* xsrc = reinterpret_cast<const f32x4*>(x + (size_t)i0 * INF);
  f32x4* xdst = reinterpret_cast<f32x4*>(&xs[0][0]);
  #pragma unroll
  for (int u = 0; u < (32 * INF / 4) / 256; ++u)
    xdst[u * 256 + t] = xsrc[u * 256 + t];
  __syncthreads();

  const int c  = t & 127;
  const int rg = t >> 7;  // 0/1 -> rows rg*16 .. rg*16+15
  float acc[16];
  #pragma unroll
  for (int r = 0; r < 16; ++r) acc[r] = 0.f;
  for (int k = 0; k < INF; ++k) {
    float wv = W[k * OUTF + c];
    #pragma unroll
    for (int r = 0; r < 16; ++r) acc[r] += xs[rg * 16 + r][k] * wv;
  }
  #pragma unroll
  for (int r = 0; r < 16; ++r) hs[rg * 16 + r][c] = acc[r];
  __syncthreads();

  const int wv = t >> 6, lane = t & 63;
  for (int r = wv; r < 32; r += 4) {
    float h0 = hs[r][lane * 2], h1 = hs[r][lane * 2 + 1];
    float s1 = h0 * a[lane * 2] + h1 * a[lane * 2 + 1];
    float s2 = h0 * a[OUTF + lane * 2] + h1 * a[OUTF + lane * 2 + 1];
    #pragma unroll
    for (int off = 32; off; off >>= 1) {
      s1 += __shfl_down(s1, off);
      s2 += __shfl_down(s2, off);
    }
    if (lane == 0) { f1[i0 + r] = s1 * LOG2E; f2[i0 + r] = s2 * LOG2E; }
  }

  const int col = t >> 1, seg = t & 1;
  bf16x8 v0, v1;
  #pragma unroll
  for (int r = 0; r < 8; ++r) v0[r] = (__bf16)hs[seg * 16 + r][col];
  #pragma unroll
  for (int r = 0; r < 8; ++r) v1[r] = (__bf16)hs[seg * 16 + 8 + r][col];
  __bf16* hdst = ht + (size_t)col * NROW + i0 + seg * 16;
  *reinterpret_cast<bf16x8*>(hdst)     = v0;
  *reinterpret_cast<bf16x8*>(hdst + 8) = v1;
}

// ---------------------------------------------------------------------------
// katt2: one row per block, 8192 blocks. Phase 1 pure read (f2 kept in
// registers); phase 1.5 emits the packed adjacency bitmask + row sum; phase
// 2 pure register-fed write stream. 524 MB @ ~5.7 TB/s (r15) ~= copy ceiling.
// grid: NROW blocks, 256 threads
// ---------------------------------------------------------------------------
__global__ __launch_bounds__(256) void katt2(const int* __restrict__ adj,
                                             const float* __restrict__ f1,
                                             const float* __restrict__ f2,
                                             u64* __restrict__ mask,
                                             float* __restrict__ s,
                                             float* __restrict__ att) {
  const int i = blockIdx.x;
  const int t = threadIdx.x;
  const int lane = t & 63, wv = t >> 6;
  const float f1i = f1[i];
  const i32x4* arow = reinterpret_cast<const i32x4*>(adj + (size_t)i * NROW);
  const f32x4* f2v  = reinterpret_cast<const f32x4*>(f2);
  u64* mrow = mask + (size_t)i * 128;

  unsigned mynibs = 0;
  float acc = 0.f;
  f32x4 fv[8];
  #pragma unroll
  for (int it = 0; it < 8; ++it) {
    i32x4 av = __builtin_nontemporal_load(arow + it * 256 + t);
    fv[it] = f2v[it * 256 + t];
    unsigned nib = (av[0] > 0) | ((av[1] > 0) << 1) | ((av[2] > 0) << 2) |
                   ((av[3] > 0) << 3);
    mynibs |= nib << (it * 4);
    #pragma unroll
    for (int b = 0; b < 4; ++b) {
      float e = f1i + fv[it][b];
      e = e > 0.f ? e : 0.01f * e;
      acc += ((nib >> b) & 1u) ? __builtin_exp2f(e) : 0.f;
    }
  }

  #pragma unroll
  for (int it = 0; it < 8; ++it) {
    u64 m = (u64)((mynibs >> (it * 4)) & 0xFu) << (4 * (lane & 15));
    #pragma unroll
    for (int d = 1; d < 16; d <<= 1) m |= __shfl_xor(m, d);
    if ((lane & 15) == 0) mrow[it * 16 + (t >> 4)] = m;
  }
  #pragma unroll
  for (int off = 32; off; off >>= 1) acc += __shfl_down(acc, off);
  __shared__ float red[4];
  if (lane == 0) red[wv] = acc;
  __syncthreads();
  const float srow = red[0] + red[1] + red[2] + red[3];
  if (t == 0) s[i] = srow;
  const float inv_s = 1.0f / srow;

  f32x4* adst = reinterpret_cast<f32x4*>(att + (size_t)i * NROW);
  #pragma unroll
  for (int it = 0; it < 8; ++it) {
    const unsigned nib = (mynibs >> (it * 4)) & 0xFu;
    f32x4 o;
    #pragma unroll
    for (int b = 0; b < 4; ++b) {
      float e = f1i + fv[it][b];
      e = e > 0.f ? e : 0.01f * e;
      o[b] = ((nib >> b) & 1u) ? __builtin_exp2f(e) * inv_s : 0.f;
    }
    adst[it * 256 + t] = o;
  }
}

// ---------------------------------------------------------------------------
// kpv: out0 = P @ h. Merge of the two proven halves:
//  - B transport: LDS-staged, double-buffered (r16 — works; direct-L2 r17
//    regressed on load latency).
//  - Wave decomposition: 2x2 (r17, correctness-proven) — wave (wr,wc) owns
//    rows wr*32..+31 x cols wc*64..+63, so per iter it reads only 8
//    ds_read_b128 of B instead of 16, cutting the LDS-pipe issue floor
//    (r16's binding resource) by ~30%. A-gen doubles (32 exp2/iter) on the
//    idle VALU.
// LDS: 36 (B dbuf) + 8.5 (mask [64][17] pad) + 4 (f2s) = 48.5 KB -> 3 blk/CU.
// grid: (NROW/64)*KSPLIT = 1024 blocks, 256 threads
// ---------------------------------------------------------------------------
__global__ __launch_bounds__(256, 3) void kpv(const __bf16* __restrict__ ht,
                                              const float* __restrict__ f1,
                                              const float* __restrict__ f2,
                                              const float* __restrict__ sum,
                                              const u64* __restrict__ mask,
                                              float* __restrict__ out0) {
  __shared__ __bf16 bs[2][128][72];  // 36 KB, double-buffered B tile
  __shared__ float f2s[KCHUNK];      // 4 KB
  __shared__ u64 ms[64][17];         // 8.5 KB
  const int mb = blockIdx.x / KSPLIT;
  const int ks = blockIdx.x % KSPLIT;
  const int t    = threadIdx.x;
  const int w    = t >> 6;
  const int wr   = w >> 1;        // row half (0/1)
  const int wc   = w & 1;         // col half (0/1)
  const int lane = t & 63;
  const int lr = lane & 15;
  const int lc = lane >> 4;
  const int row0 = mb * 64;
  const int j0 = ks * KCHUNK;

  // ---- prologue: stage f2 chunk, mask chunk, B tile 0 ----
  {
    reinterpret_cast<f32x4*>(f2s)[t] =
        reinterpret_cast<const f32x4*>(f2 + j0)[t];
    const int r = t >> 2, q = (t & 3) * 4;
    const u64* msrc = mask + (size_t)(row0 + r) * 128 + (j0 >> 6) + q;
    ms[r][q]     = msrc[0];
    ms[r][q + 1] = msrc[1];
    ms[r][q + 2] = msrc[2];
    ms[r][q + 3] = msrc[3];
  }
  const int sr = t >> 1, sc = (t & 1) * 32;  // B staging map
  const __bf16* sgsrc = ht + (size_t)sr * NROW + j0 + sc;
  {
    bf16x8 st0 = *reinterpret_cast<const bf16x8*>(sgsrc);
    bf16x8 st1 = *reinterpret_cast<const bf16x8*>(sgsrc + 8);
    bf16x8 st2 = *reinterpret_cast<const bf16x8*>(sgsrc + 16);
    bf16x8 st3 = *reinterpret_cast<const bf16x8*>(sgsrc + 24);
    *reinterpret_cast<bf16x8*>(&bs[0][sr][sc])      = st0;
    *reinterpret_cast<bf16x8*>(&bs[0][sr][sc + 8])  = st1;
    *reinterpret_cast<bf16x8*>(&bs[0][sr][sc + 16]) = st2;
    *reinterpret_cast<bf16x8*>(&bs[0][sr][sc + 24]) = st3;
  }
  __syncthreads();

  const float f1r0 = f1[row0 + wr * 32 + lr];
  const float f1r1 = f1[row0 + wr * 32 + 16 + lr];

  f32x4 acc[2][4];
  #pragma unroll
  for (int rt = 0; rt < 2; ++rt)
    #pragma unroll
    for (int n = 0; n < 4; ++n) acc[rt][n] = (f32x4){0.f, 0.f, 0.f, 0.f};

  for (int it = 0; it < NIT; ++it) {
    const int cur = it & 1;
    const bool more = (it + 1) < NIT;
    const int kk = it * 64;

    // ---- issue B staging loads for tile t+1 (only vmcnt ops in loop) ----
    bf16x8 st0, st1, st2, st3;
    if (more) {
      const __bf16* sg = sgsrc + (it + 1) * 64;
      st0 = *reinterpret_cast<const bf16x8*>(sg);
      st1 = *reinterpret_cast<const bf16x8*>(sg + 8);
      st2 = *reinterpret_cast<const bf16x8*>(sg + 16);
      st3 = *reinterpret_cast<const bf16x8*>(sg + 24);
    }

    // ---- A-fragments for 2 row-tiles from mask + f2s (VALU) ----
    const u64 mw0 = ms[wr * 32 + lr][it];
    const u64 mw1 = ms[wr * 32 + 16 + lr][it];
    bf16x8 afrag[2][2];
    #pragma unroll
    for (int h = 0; h < 2; ++h) {
      const int base = kk + h * 32 + lc * 8;
      const f32x4 fa = *reinterpret_cast<const f32x4*>(&f2s[base]);
      const f32x4 fb = *reinterpret_cast<const f32x4*>(&f2s[base + 4]);
      const unsigned bits0 = (unsigned)(mw0 >> (h * 32 + lc * 8)) & 0xFFu;
      const unsigned bits1 = (unsigned)(mw1 >> (h * 32 + lc * 8)) & 0xFFu;
      #pragma unroll
      for (int i2 = 0; i2 < 8; ++i2) {
        const float fval = (i2 < 4) ? fa[i2] : fb[i2 - 4];
        float e0 = f1r0 + fval;
        e0 = e0 > 0.f ? e0 : 0.01f * e0;
        afrag[0][h][i2] =
            (__bf16)(((bits0 >> i2) & 1u) ? __builtin_exp2f(e0) : 0.f);
        float e1 = f1r1 + fval;
        e1 = e1 > 0.f ? e1 : 0.01f * e1;
        afrag[1][h][i2] =
            (__bf16)(((bits1 >> i2) & 1u) ? __builtin_exp2f(e1) : 0.f);
      }
    }

    // ---- B from LDS (8 b128: only this wave's 64-col slice) + MFMA ----
    #pragma unroll
    for (int n = 0; n < 4; ++n) {
      bf16x8 b0 = *reinterpret_cast<const bf16x8*>(
          &bs[cur][wc * 64 + n * 16 + lr][lc * 8]);
      bf16x8 b1 = *reinterpret_cast<const bf16x8*>(
          &bs[cur][wc * 64 + n * 16 + lr][lc * 8 + 32]);
      #pragma unroll
      for (int rt = 0; rt < 2; ++rt) {
        acc[rt][n] = __builtin_amdgcn_mfma_f32_16x16x32_bf16(
            afrag[rt][0], b0, acc[rt][n], 0, 0, 0);
        acc[rt][n] = __builtin_amdgcn_mfma_f32_16x16x32_bf16(
            afrag[rt][1], b1, acc[rt][n], 0, 0, 0);
      }
    }

    // ---- write staged tile, one barrier per iter ----
    if (more) {
      *reinterpret_cast<bf16x8*>(&bs[cur ^ 1][sr][sc])      = st0;
      *reinterpret_cast<bf16x8*>(&bs[cur ^ 1][sr][sc + 8])  = st1;
      *reinterpret_cast<bf16x8*>(&bs[cur ^ 1][sr][sc + 16]) = st2;
      *reinterpret_cast<bf16x8*>(&bs[cur ^ 1][sr][sc + 24]) = st3;
      __syncthreads();
    }
  }

  // ---- epilogue: scale by 1/s, atomic accumulate (r17 mapping) ----
  #pragma unroll
  for (int rt = 0; rt < 2; ++rt) {
    float inv_sD[4];
    #pragma unroll
    for (int i2 = 0; i2 < 4; ++i2)
      inv_sD[i2] = 1.0f / sum[row0 + wr * 32 + rt * 16 + lc * 4 + i2];
    #pragma unroll
    for (int n = 0; n < 4; ++n) {
      #pragma unroll
      for (int i2 = 0; i2 < 4; ++i2) {
        atomicAdd(&out0[(size_t)(row0 + wr * 32 + rt * 16 + lc * 4 + i2) * OUTF +
                        wc * 64 + n * 16 + lr],
                  acc[rt][n][i2] * inv_sD[i2]);
      }
    }
  }
}

// ---------------------------------------------------------------------------
extern "C" void kernel_launch(void* const* d_in, const int* in_sizes, int n_in,
                              void* d_out, int out_size, void* d_ws, size_t ws_size,
                              hipStream_t stream) {
  const float* x   = (const float*)d_in[0];
  const int*   adj = (const int*)d_in[1];
  const float* W   = (const float*)d_in[2];
  const float* a   = (const float*)d_in[3];

  float* out0 = (float*)d_out;                       // 8192 x 128
  float* att  = (float*)d_out + (size_t)NROW * OUTF; // 8192 x 8192

  char* ws = (char*)d_ws;
  __bf16* ht = (__bf16*)ws;                                         // 2 MB
  u64* mask = (u64*)(ws + (2 << 20));                               // 8 MB
  float* f1 = (float*)(ws + (10 << 20));
  float* f2 = (float*)(ws + (10 << 20) + 32 * 1024);
  float* s  = (float*)(ws + (10 << 20) + 64 * 1024);

  hipMemsetAsync(out0, 0, (size_t)NROW * OUTF * sizeof(float), stream);
  k1<<<NROW / 32, 256, 0, stream>>>(x, W, a, ht, f1, f2);
  katt2<<<NROW, 256, 0, stream>>>(adj, f1, f2, mask, s, att);
  kpv<<<(NROW / 64) * KSPLIT, 256, 0, stream>>>(ht, f1, f2, s, mask, out0);
}

// Round 19
// 179.380 us; speedup vs baseline: 1.1386x; 1.1386x over previous
//
#include <hip/hip_runtime.h>
#include <hip/hip_bf16.h>

constexpr int NROW = 8192;
constexpr int INF  = 256;
constexpr int OUTF = 128;
constexpr int KSPLIT = 8;
constexpr int KCHUNK = NROW / KSPLIT; // 1024
constexpr int NIT    = KCHUNK / 64;   // 16 k-iterations per block
#define LOG2E 1.4426950408889634f

typedef __bf16 bf16x8 __attribute__((ext_vector_type(8)));
typedef float  f32x4  __attribute__((ext_vector_type(4)));
typedef int    i32x4  __attribute__((ext_vector_type(4)));
typedef unsigned long long u64;

// global -> LDS direct async copy, 16 B per lane. Dest is wave-uniform base
// + lane*16 (linear); per-lane GLOBAL address carries the swizzle (m173).
#define GLOAD_LDS16(gsrc, ldst)                                           \
  __builtin_amdgcn_global_load_lds(                                       \
      (const __attribute__((address_space(1))) unsigned int*)(gsrc),      \
      (__attribute__((address_space(3))) unsigned int*)(ldst), 16, 0, 0)

// ---------------------------------------------------------------------------
// k1: h = x@W (f32 accum); f1 = (h@a1)*log2e, f2 = (h@a2)*log2e; ht = h^T bf16
// grid: NROW/32 blocks, 256 threads
// ---------------------------------------------------------------------------
__global__ __launch_bounds__(256) void k1(const float* __restrict__ x,
                                          const float* __restrict__ W,
                                          const float* __restrict__ a,
                                          __bf16* __restrict__ ht,
                                          float* __restrict__ f1,
                                          float* __restrict__ f2) {
  __shared__ float xs[32][INF];   // 32 KB
  __shared__ float hs[32][OUTF];  // 16 KB
  const int t  = threadIdx.x;
  const int i0 = blockIdx.x * 32;

  const f32x4* xsrc = reinterpret_cast<const f32x4*>(x + (size_t)i0 * INF);
  f32x4* xdst = reinterpret_cast<f32x4*>(&xs[0][0]);
  #pragma unroll
  for (int u = 0; u < (32 * INF / 4) / 256; ++u)
    xdst[u * 256 + t] = xsrc[u * 256 + t];
  __syncthreads();

  const int c  = t & 127;
  const int rg = t >> 7;  // 0/1 -> rows rg*16 .. rg*16+15
  float acc[16];
  #pragma unroll
  for (int r = 0; r < 16; ++r) acc[r] = 0.f;
  for (int k = 0; k < INF; ++k) {
    float wv = W[k * OUTF + c];
    #pragma unroll
    for (int r = 0; r < 16; ++r) acc[r] += xs[rg * 16 + r][k] * wv;
  }
  #pragma unroll
  for (int r = 0; r < 16; ++r) hs[rg * 16 + r][c] = acc[r];
  __syncthreads();

  const int wv = t >> 6, lane = t & 63;
  for (int r = wv; r < 32; r += 4) {
    float h0 = hs[r][lane * 2], h1 = hs[r][lane * 2 + 1];
    float s1 = h0 * a[lane * 2] + h1 * a[lane * 2 + 1];
    float s2 = h0 * a[OUTF + lane * 2] + h1 * a[OUTF + lane * 2 + 1];
    #pragma unroll
    for (int off = 32; off; off >>= 1) {
      s1 += __shfl_down(s1, off);
      s2 += __shfl_down(s2, off);
    }
    if (lane == 0) { f1[i0 + r] = s1 * LOG2E; f2[i0 + r] = s2 * LOG2E; }
  }

  const int col = t >> 1, seg = t & 1;
  bf16x8 v0, v1;
  #pragma unroll
  for (int r = 0; r < 8; ++r) v0[r] = (__bf16)hs[seg * 16 + r][col];
  #pragma unroll
  for (int r = 0; r < 8; ++r) v1[r] = (__bf16)hs[seg * 16 + 8 + r][col];
  __bf16* hdst = ht + (size_t)col * NROW + i0 + seg * 16;
  *reinterpret_cast<bf16x8*>(hdst)     = v0;
  *reinterpret_cast<bf16x8*>(hdst + 8) = v1;
}

// ---------------------------------------------------------------------------
// katt2: one row per block, 8192 blocks. Phase 1 pure read (f2 kept in
// registers); phase 1.5 emits the packed adjacency bitmask + row sum; phase
// 2 pure register-fed write stream. 524 MB @ ~5.7 TB/s (r15) ~= copy ceiling.
// grid: NROW blocks, 256 threads
// ---------------------------------------------------------------------------
__global__ __launch_bounds__(256) void katt2(const int* __restrict__ adj,
                                             const float* __restrict__ f1,
                                             const float* __restrict__ f2,
                                             u64* __restrict__ mask,
                                             float* __restrict__ s,
                                             float* __restrict__ att) {
  const int i = blockIdx.x;
  const int t = threadIdx.x;
  const int lane = t & 63, wv = t >> 6;
  const float f1i = f1[i];
  const i32x4* arow = reinterpret_cast<const i32x4*>(adj + (size_t)i * NROW);
  const f32x4* f2v  = reinterpret_cast<const f32x4*>(f2);
  u64* mrow = mask + (size_t)i * 128;

  unsigned mynibs = 0;
  float acc = 0.f;
  f32x4 fv[8];
  #pragma unroll
  for (int it = 0; it < 8; ++it) {
    i32x4 av = __builtin_nontemporal_load(arow + it * 256 + t);
    fv[it] = f2v[it * 256 + t];
    unsigned nib = (av[0] > 0) | ((av[1] > 0) << 1) | ((av[2] > 0) << 2) |
                   ((av[3] > 0) << 3);
    mynibs |= nib << (it * 4);
    #pragma unroll
    for (int b = 0; b < 4; ++b) {
      float e = f1i + fv[it][b];
      e = e > 0.f ? e : 0.01f * e;
      acc += ((nib >> b) & 1u) ? __builtin_exp2f(e) : 0.f;
    }
  }

  #pragma unroll
  for (int it = 0; it < 8; ++it) {
    u64 m = (u64)((mynibs >> (it * 4)) & 0xFu) << (4 * (lane & 15));
    #pragma unroll
    for (int d = 1; d < 16; d <<= 1) m |= __shfl_xor(m, d);
    if ((lane & 15) == 0) mrow[it * 16 + (t >> 4)] = m;
  }
  #pragma unroll
  for (int off = 32; off; off >>= 1) acc += __shfl_down(acc, off);
  __shared__ float red[4];
  if (lane == 0) red[wv] = acc;
  __syncthreads();
  const float srow = red[0] + red[1] + red[2] + red[3];
  if (t == 0) s[i] = srow;
  const float inv_s = 1.0f / srow;

  f32x4* adst = reinterpret_cast<f32x4*>(att + (size_t)i * NROW);
  #pragma unroll
  for (int it = 0; it < 8; ++it) {
    const unsigned nib = (mynibs >> (it * 4)) & 0xFu;
    f32x4 o;
    #pragma unroll
    for (int b = 0; b < 4; ++b) {
      float e = f1i + fv[it][b];
      e = e > 0.f ? e : 0.01f * e;
      o[b] = ((nib >> b) & 1u) ? __builtin_exp2f(e) * inv_s : 0.f;
    }
    adst[it * 256 + t] = o;
  }
}

// ---------------------------------------------------------------------------
// kpv: out0 = P @ h — r16 structure (64-row block, wave w owns rows w*16..,
// LDS-dbuf B) with ONE change: B staging via global_load_lds width-16.
// Removes the per-iter register round-trip (global->VGPR->ds_write forced a
// vmcnt(0) before the ds_writes every iteration). LDS dest must be LINEAR
// (rule #21), so no row padding; bank conflicts avoided by content-swizzle:
// LDS[row][c16] holds ht 16B-unit (c16 ^ (row&7)) — applied on the GLOBAL
// source address at stage time and on the ds_read address at use time.
// LDS: 32 (B dbuf, linear) + 8.5 (mask) + 4 (f2s) = 44.5 KB -> 3 blk/CU.
// grid: (NROW/64)*KSPLIT = 1024 blocks, 256 threads
// ---------------------------------------------------------------------------
__global__ __launch_bounds__(256, 3) void kpv(const __bf16* __restrict__ ht,
                                              const float* __restrict__ f1,
                                              const float* __restrict__ f2,
                                              const float* __restrict__ sum,
                                              const u64* __restrict__ mask,
                                              float* __restrict__ out0) {
  __shared__ __bf16 bs[2][128 * 64];  // 32 KB, linear (global_load_lds dest)
  __shared__ float f2s[KCHUNK];       // 4 KB
  __shared__ u64 ms[64][17];          // 8.5 KB
  const int mb = blockIdx.x / KSPLIT;
  const int ks = blockIdx.x % KSPLIT;
  const int t    = threadIdx.x;
  const int w    = t >> 6;
  const int lane = t & 63;
  const int lr = lane & 15;
  const int lc = lane >> 4;
  const int row0 = mb * 64;
  const int j0 = ks * KCHUNK;

  // staging geometry: 16B-unit u = w*256 + q*64 + lane; B-row = u>>3,
  // c16 = u&7; global col unit = c16 ^ (row&7)  (content swizzle).
  const int srow = w * 32 + (lane >> 3);                    // + q*8
  const int sgcol = ((lane & 7) ^ ((lane >> 3) & 7)) << 3;  // bf16 offset
  const __bf16* sgbase = ht + (size_t)srow * NROW + j0 + sgcol;
  const int ldsu = (w * 256 + (lane & 63) * 0) * 8;         // wave base (bf16)

  // ---- prologue: stage f2 chunk, mask chunk, B tile 0 (async) ----
  reinterpret_cast<f32x4*>(f2s)[t] =
      reinterpret_cast<const f32x4*>(f2 + j0)[t];
  {
    const int r = t >> 2, q = (t & 3) * 4;
    const u64* msrc = mask + (size_t)(row0 + r) * 128 + (j0 >> 6) + q;
    ms[r][q]     = msrc[0];
    ms[r][q + 1] = msrc[1];
    ms[r][q + 2] = msrc[2];
    ms[r][q + 3] = msrc[3];
  }
  #pragma unroll
  for (int q = 0; q < 4; ++q)
    GLOAD_LDS16(sgbase + (size_t)(q * 8) * NROW,
                &bs[0][ldsu + q * 64 * 8]);
  __syncthreads();

  const int   rloc = w * 16 + lr;
  const float f1r  = f1[row0 + rloc];
  const int   s0 = (lc ^ (lr & 7)) << 3;         // swizzled read offsets
  const int   s1 = ((lc + 4) ^ (lr & 7)) << 3;

  f32x4 acc[8];
  #pragma unroll
  for (int n = 0; n < 8; ++n) acc[n] = (f32x4){0.f, 0.f, 0.f, 0.f};

  for (int it = 0; it < NIT; ++it) {
    const int cur = it & 1;
    const bool more = (it + 1) < NIT;
    const int kk = it * 64;

    // ---- async-stage B tile t+1 (no register round-trip; drains at the
    //      barrier's vmcnt(0), covered by A-gen + MFMA below) ----
    if (more) {
      #pragma unroll
      for (int q = 0; q < 4; ++q)
        GLOAD_LDS16(sgbase + (size_t)(q * 8) * NROW + kk + 64,
                    &bs[cur ^ 1][ldsu + q * 64 * 8]);
    }

    // ---- A-fragments from mask + f2s (LDS + VALU only) ----
    const u64 mw = ms[rloc][it];
    bf16x8 afrag[2];
    #pragma unroll
    for (int h = 0; h < 2; ++h) {
      const unsigned bits = (unsigned)(mw >> (h * 32 + lc * 8)) & 0xFFu;
      const int base = kk + h * 32 + lc * 8;
      #pragma unroll
      for (int i2 = 0; i2 < 8; ++i2) {
        float e = f1r + f2s[base + i2];
        e = e > 0.f ? e : 0.01f * e;
        afrag[h][i2] = (__bf16)(((bits >> i2) & 1u) ? __builtin_exp2f(e) : 0.f);
      }
    }

    // ---- B from LDS (swizzled addr) + MFMA ----
    #pragma unroll
    for (int n = 0; n < 8; ++n) {
      const int rb = (n * 16 + lr) * 64;
      bf16x8 b0 = *reinterpret_cast<const bf16x8*>(&bs[cur][rb + s0]);
      bf16x8 b1 = *reinterpret_cast<const bf16x8*>(&bs[cur][rb + s1]);
      acc[n] = __builtin_amdgcn_mfma_f32_16x16x32_bf16(afrag[0], b0, acc[n], 0, 0, 0);
      acc[n] = __builtin_amdgcn_mfma_f32_16x16x32_bf16(afrag[1], b1, acc[n], 0, 0, 0);
    }

    if (more) __syncthreads();  // drains vmcnt (staged tile) + lgkm
  }

  // ---- epilogue: scale by 1/s, atomic accumulate ----
  float inv_sD[4];
  #pragma unroll
  for (int i2 = 0; i2 < 4; ++i2)
    inv_sD[i2] = 1.0f / sum[row0 + w * 16 + lc * 4 + i2];
  #pragma unroll
  for (int n = 0; n < 8; ++n) {
    #pragma unroll
    for (int i2 = 0; i2 < 4; ++i2) {
      atomicAdd(&out0[(size_t)(row0 + w * 16 + lc * 4 + i2) * OUTF + n * 16 + lr],
                acc[n][i2] * inv_sD[i2]);
    }
  }
}

// ---------------------------------------------------------------------------
extern "C" void kernel_launch(void* const* d_in, const int* in_sizes, int n_in,
                              void* d_out, int out_size, void* d_ws, size_t ws_size,
                              hipStream_t stream) {
  const float* x   = (const float*)d_in[0];
  const int*   adj = (const int*)d_in[1];
  const float* W   = (const float*)d_in[2];
  const float* a   = (const float*)d_in[3];

  float* out0 = (float*)d_out;                       // 8192 x 128
  float* att  = (float*)d_out + (size_t)NROW * OUTF; // 8192 x 8192

  char* ws = (char*)d_ws;
  __bf16* ht = (__bf16*)ws;                                         // 2 MB
  u64* mask = (u64*)(ws + (2 << 20));                               // 8 MB
  float* f1 = (float*)(ws + (10 << 20));
  float* f2 = (float*)(ws + (10 << 20) + 32 * 1024);
  float* s  = (float*)(ws + (10 << 20) + 64 * 1024);

  hipMemsetAsync(out0, 0, (size_t)NROW * OUTF * sizeof(float), stream);
  k1<<<NROW / 32, 256, 0, stream>>>(x, W, a, ht, f1, f2);
  katt2<<<NROW, 256, 0, stream>>>(adj, f1, f2, mask, s, att);
  kpv<<<(NROW / 64) * KSPLIT, 256, 0, stream>>>(ht, f1, f2, s, mask, out0);
}